// Round 14
// baseline (71.824 us; speedup 1.0000x reference)
//
#include <hip/hip_runtime.h>
#include <hip/hip_bf16.h>
#include <math.h>

#define NQ 50000
#define NS 50000
#define KK 32
#define CF 64      // feat channels
#define CW 67      // conv input channels (3 + 64)
#define CO 64      // output channels
#define WAVES 4
#define GRIDM 768             // 3 blocks/CU; (256,3) proven clean codegen point
#define GS2 (GRIDM * WAVES)   // 3072 queries per grid-stride step

typedef __attribute__((ext_vector_type(8))) short bf16x8;
typedef __attribute__((ext_vector_type(16))) float f32x16;

__device__ inline short f2b(float x) {
    union { __hip_bfloat16 b; short s; } u;
    u.b = __float2bfloat16(x);   // RNE
    return u.s;
}

__device__ inline bf16x8 pack2(const float4 a, const float4 b) {
    bf16x8 r;
    r[0] = f2b(a.x); r[1] = f2b(a.y); r[2] = f2b(a.z); r[3] = f2b(a.w);
    r[4] = f2b(b.x); r[5] = f2b(b.y); r[6] = f2b(b.z); r[7] = f2b(b.w);
    return r;
}

__device__ inline bf16x8 zero8() {
    bf16x8 r;
#pragma unroll
    for (int j = 0; j < 8; ++j) r[j] = 0;
    return r;
}

// feat f32 [NS][64] -> bf16 table [NS+1][64] (row NS = zeros).
__global__ __launch_bounds__(256) void gc_tobf16(const float* __restrict__ feat,
                                                 bf16x8* __restrict__ fbf)
{
    const int i = blockIdx.x * 256 + threadIdx.x;     // short8 index
    if (i >= (NS + 1) * CF / 8) return;
    bf16x8 r;
    if (i < NS * CF / 8) {
        const float4* fp = (const float4*)feat + (size_t)i * 2;
        r = pack2(fp[0], fp[1]);
    } else {
        r = zero8();
    }
    fbf[i] = r;
}

// Pack points: sp4[NS+1] = (x,y,z,0) with zero pad row; qp4[NQ] = (x,y,z,0).
__global__ __launch_bounds__(256) void gc_packpts(const float* __restrict__ sp,
                                                  const float* __restrict__ qp,
                                                  float4* __restrict__ sp4,
                                                  float4* __restrict__ qp4)
{
    const int i = blockIdx.x * 256 + threadIdx.x;
    if (i <= NS) {
        float4 v = make_float4(0.f, 0.f, 0.f, 0.f);
        if (i < NS) { v.x = sp[i * 3 + 0]; v.y = sp[i * 3 + 1]; v.z = sp[i * 3 + 2]; }
        sp4[i] = v;
    }
    if (i < NQ) {
        float4 v = make_float4(qp[i * 3 + 0], qp[i * 3 + 1], qp[i * 3 + 2], 0.f);
        qp4[i] = v;
    }
}

// Load one pipeline slot (flat refs, no struct -> no scratch).
// 6 VMEM per stage: 4 feat (16B) + 1 sp4 (16B) + (inds prefetched by caller);
// qp4 is wave-uniform -> s_load_dwordx4.
template <bool TAB>
__device__ inline void load_stage(const bf16x8* __restrict__ fbf,
                                  const float* __restrict__ feat,
                                  const float4* __restrict__ sp4,
                                  const float4* __restrict__ qp4,
                                  const float* __restrict__ sp,
                                  const float* __restrict__ qp,
                                  int ii, int q, int half,
                                  bf16x8& F0, bf16x8& F1, bf16x8& F2, bf16x8& F3,
                                  float& sx, float& sy, float& sz,
                                  float& qx, float& qy, float& qz)
{
    if (TAB) {
        const bf16x8* frow = fbf + (size_t)ii * 8;   // row NS is zeros
        F0 = frow[half]; F1 = frow[2 + half]; F2 = frow[4 + half]; F3 = frow[6 + half];
        const float4 s4 = sp4[ii];                   // row NS is zeros
        sx = s4.x; sy = s4.y; sz = s4.z;
        const float4 q4 = qp4[q];                    // wave-uniform -> s_load
        qx = q4.x; qy = q4.y; qz = q4.z;
    } else {
        const bool v = (ii < NS);
        const int iic = v ? ii : 0;
        const float4* fp = (const float4*)(feat + (size_t)iic * CF);
        F0 = pack2(fp[half * 2], fp[half * 2 + 1]);
        F1 = pack2(fp[4 + half * 2], fp[4 + half * 2 + 1]);
        F2 = pack2(fp[8 + half * 2], fp[8 + half * 2 + 1]);
        F3 = pack2(fp[12 + half * 2], fp[12 + half * 2 + 1]);
        if (!v) { F0 = zero8(); F1 = zero8(); F2 = zero8(); F3 = zero8(); }
        const int iis = v ? ii : 0;
        sx = sp[iis * 3 + 0]; sy = sp[iis * 3 + 1]; sz = sp[iis * 3 + 2];
        qx = qp[q * 3 + 0];   qy = qp[q * 3 + 1];   qz = qp[q * 3 + 2];
    }
}

// One wave = one query per phase. M=32 neighbors, N=64 (2 tiles of 32),
// K=80 (k0..63 feat via bf16 table, k64..66 rel coords).
// 2-slot rotation-free pipeline (R13 structure, proven 76 VGPR / no spill).
template <bool TAB, bool MIN>
__global__ __launch_bounds__(256, 3) void gc_mfma(
    const float* __restrict__ qp,
    const float* __restrict__ sp,
    const float* __restrict__ feat,
    const bf16x8* __restrict__ fbf,   // [NS+1][8] short8 rows
    const float4* __restrict__ sp4,   // [NS+1] xyz0, zero pad row
    const float4* __restrict__ qp4,   // [NQ] xyz0
    const float* __restrict__ w,      // [64][67]
    const int*   __restrict__ inds,
    float* __restrict__ zmax,         // d_out [NQ][64]
    float* __restrict__ zmin,         // ws (optional)
    float* __restrict__ partials)     // [GRIDM][128]
{
    __shared__ float red[WAVES][128];

    const int tid  = threadIdx.x;
    const int lane = tid & 63;
    const int wv   = tid >> 6;
    const int col  = lane & 31;
    const int half = lane >> 5;

    // ---- B fragments (weights), register-resident, built once ----
    bf16x8 bfrag[5][2];
#pragma unroll
    for (int c = 0; c < 5; ++c) {
#pragma unroll
        for (int t = 0; t < 2; ++t) {
            const int o = t * 32 + col;
            bf16x8 r;
#pragma unroll
            for (int j = 0; j < 8; ++j) {
                const int k = c * 16 + half * 8 + j;
                float v = 0.f;
                if (k < 64)      v = w[o * CW + 3 + k];
                else if (k < 67) v = w[o * CW + (k - 64)];
                r[j] = f2b(v);
            }
            bfrag[c][t] = r;
        }
    }

    float csum0 = 0.f, csum1 = 0.f, csq0 = 0.f, csq1 = 0.f;

    auto compute = [&](const bf16x8& F0, const bf16x8& F1,
                       const bf16x8& F2, const bf16x8& F3,
                       float sx, float sy, float sz,
                       float qx, float qy, float qz,
                       int ii, int q) {
        const bool vc = (ii < NS);
        bf16x8 a4 = zero8();
        if (half == 0) {
            a4[0] = f2b(vc ? sx - qx : 0.f);
            a4[1] = f2b(vc ? sy - qy : 0.f);
            a4[2] = f2b(vc ? sz - qz : 0.f);
        }

        f32x16 acc0, acc1;
#pragma unroll
        for (int r = 0; r < 16; ++r) { acc0[r] = 0.f; acc1[r] = 0.f; }
        acc0 = __builtin_amdgcn_mfma_f32_32x32x16_bf16(F0, bfrag[0][0], acc0, 0, 0, 0);
        acc1 = __builtin_amdgcn_mfma_f32_32x32x16_bf16(F0, bfrag[0][1], acc1, 0, 0, 0);
        acc0 = __builtin_amdgcn_mfma_f32_32x32x16_bf16(F1, bfrag[1][0], acc0, 0, 0, 0);
        acc1 = __builtin_amdgcn_mfma_f32_32x32x16_bf16(F1, bfrag[1][1], acc1, 0, 0, 0);
        acc0 = __builtin_amdgcn_mfma_f32_32x32x16_bf16(F2, bfrag[2][0], acc0, 0, 0, 0);
        acc1 = __builtin_amdgcn_mfma_f32_32x32x16_bf16(F2, bfrag[2][1], acc1, 0, 0, 0);
        acc0 = __builtin_amdgcn_mfma_f32_32x32x16_bf16(F3, bfrag[3][0], acc0, 0, 0, 0);
        acc1 = __builtin_amdgcn_mfma_f32_32x32x16_bf16(F3, bfrag[3][1], acc1, 0, 0, 0);
        acc0 = __builtin_amdgcn_mfma_f32_32x32x16_bf16(a4, bfrag[4][0], acc0, 0, 0, 0);
        acc1 = __builtin_amdgcn_mfma_f32_32x32x16_bf16(a4, bfrag[4][1], acc1, 0, 0, 0);

        float m0 = acc0[0], m1 = acc1[0];
        float n0 = acc0[0], n1 = acc1[0];
        float s0 = 0.f, s1 = 0.f, qq0 = 0.f, qq1 = 0.f;
#pragma unroll
        for (int r = 0; r < 16; ++r) {
            const float z0 = acc0[r], z1 = acc1[r];
            m0 = fmaxf(m0, z0); m1 = fmaxf(m1, z1);
            if (MIN) { n0 = fminf(n0, z0); n1 = fminf(n1, z1); }
            s0 += z0; s1 += z1;
            qq0 = fmaf(z0, z0, qq0); qq1 = fmaf(z1, z1, qq1);
        }
        csum0 += s0; csum1 += s1; csq0 += qq0; csq1 += qq1;

        m0 = fmaxf(m0, __shfl_xor(m0, 32));
        m1 = fmaxf(m1, __shfl_xor(m1, 32));
        zmax[q * CO + half * 32 + col] = half ? m1 : m0;
        if (MIN) {
            n0 = fminf(n0, __shfl_xor(n0, 32));
            n1 = fminf(n1, __shfl_xor(n1, 32));
            zmin[q * CO + half * 32 + col] = half ? n1 : n0;
        }
    };

    // ---- slot registers (flat, statically named) ----
    bf16x8 A0, A1, A2, A3; float Asx, Asy, Asz, Aqx, Aqy, Aqz; int iA;
    bf16x8 B0, B1, B2, B3; float Bsx, Bsy, Bsz, Bqx, Bqy, Bqz; int iB;

    // ---- prologue ----
    const int q0 = blockIdx.x * WAVES + wv;   // < GS2 <= NQ
    int qA = q0, qB = q0 + GS2;               // qB < 2*GS2 <= NQ always
    iA = inds[qA * KK + col];
    load_stage<TAB>(fbf, feat, sp4, qp4, sp, qp, iA, qA, half,
                    A0, A1, A2, A3, Asx, Asy, Asz, Aqx, Aqy, Aqz);
    iB = inds[qB * KK + col];
    load_stage<TAB>(fbf, feat, sp4, qp4, sp, qp, iB, qB, half,
                    B0, B1, B2, B3, Bsx, Bsy, Bsz, Bqx, Bqy, Bqz);
    int jA = (q0 + 2 * GS2 < NQ) ? inds[(q0 + 2 * GS2) * KK + col] : 0;
    int jB = (q0 + 3 * GS2 < NQ) ? inds[(q0 + 3 * GS2) * KK + col] : 0;

    for (;;) {
        // ---- phase A: compute slot A, then refill it 2 steps ahead ----
        compute(A0, A1, A2, A3, Asx, Asy, Asz, Aqx, Aqy, Aqz, iA, qA);
        {
            const int qn = qA + 2 * GS2;
            if (qn < NQ) {
                iA = jA;
                load_stage<TAB>(fbf, feat, sp4, qp4, sp, qp, iA, qn, half,
                                A0, A1, A2, A3, Asx, Asy, Asz, Aqx, Aqy, Aqz);
            }
            const int qi = qA + 4 * GS2;
            jA = (qi < NQ) ? inds[qi * KK + col] : 0;
            qA = qn;
        }
        if (qB >= NQ) break;

        // ---- phase B ----
        compute(B0, B1, B2, B3, Bsx, Bsy, Bsz, Bqx, Bqy, Bqz, iB, qB);
        {
            const int qn = qB + 2 * GS2;
            if (qn < NQ) {
                iB = jB;
                load_stage<TAB>(fbf, feat, sp4, qp4, sp, qp, iB, qn, half,
                                B0, B1, B2, B3, Bsx, Bsy, Bsz, Bqx, Bqy, Bqz);
            }
            const int qi = qB + 4 * GS2;
            jB = (qi < NQ) ? inds[qi * KK + col] : 0;
            qB = qn;
        }
        if (qA >= NQ) break;
    }

    // ---- block-level stat partials (deterministic) ----
    csum0 += __shfl_xor(csum0, 32);
    csum1 += __shfl_xor(csum1, 32);
    csq0  += __shfl_xor(csq0, 32);
    csq1  += __shfl_xor(csq1, 32);
    if (lane < 32) {
        red[wv][col]      = csum0;
        red[wv][32 + col] = csum1;
        red[wv][64 + col] = csq0;
        red[wv][96 + col] = csq1;
    }
    __syncthreads();
    if (tid < 128) {
        const float v = red[0][tid] + red[1][tid] + red[2][tid] + red[3][tid];
        partials[blockIdx.x * 128 + tid] = v;
    }
}

// One block per channel: deterministic tree reduction over GRIDM partials.
__global__ void gc_finalize(const float* __restrict__ partials,
                            const float* __restrict__ gamma,
                            const float* __restrict__ beta,
                            float* __restrict__ sb)
{
    __shared__ double rs[256], rq[256];
    const int o = blockIdx.x;     // channel
    const int t = threadIdx.x;    // 256
    double s = 0.0, qq = 0.0;
    for (int b = t; b < GRIDM; b += 256) {
        s  += (double)partials[b * 128 + o];
        qq += (double)partials[b * 128 + 64 + o];
    }
    rs[t] = s; rq[t] = qq;
    __syncthreads();
    for (int w2 = 128; w2 > 0; w2 >>= 1) {
        if (t < w2) { rs[t] += rs[t + w2]; rq[t] += rq[t + w2]; }
        __syncthreads();
    }
    if (t == 0) {
        const double n = (double)NQ * (double)KK;
        const double mean = rs[0] / n;
        const double var  = rq[0] / n - mean * mean;
        const float sc = gamma[o] * (float)(1.0 / sqrt(var + 1e-5));
        const float bi = beta[o] - (float)mean * sc;
        sb[o]      = sc;
        sb[64 + o] = bi;
    }
}

// out = leaky(scale * z + bias), in place on d_out (float4-wide).
__global__ void gc_bnact(float4* __restrict__ out,
                         const float4* __restrict__ zmin,
                         const float* __restrict__ sb,
                         int has_min)
{
    const int i  = blockIdx.x * 256 + threadIdx.x;   // < NQ*CO/4
    const int ob = (i & 15) * 4;
    const float4 s4 = *(const float4*)(sb + ob);
    const float4 b4 = *(const float4*)(sb + 64 + ob);
    float4 z4 = out[i];
    if (has_min && (s4.x < 0.f || s4.y < 0.f || s4.z < 0.f || s4.w < 0.f)) {
        const float4 n4 = zmin[i];
        if (s4.x < 0.f) z4.x = n4.x;
        if (s4.y < 0.f) z4.y = n4.y;
        if (s4.z < 0.f) z4.z = n4.z;
        if (s4.w < 0.f) z4.w = n4.w;
    }
    float4 v;
    v.x = s4.x * z4.x + b4.x;
    v.y = s4.y * z4.y + b4.y;
    v.z = s4.z * z4.z + b4.z;
    v.w = s4.w * z4.w + b4.w;
    v.x = (v.x >= 0.f) ? v.x : 0.1f * v.x;
    v.y = (v.y >= 0.f) ? v.y : 0.1f * v.y;
    v.z = (v.z >= 0.f) ? v.z : 0.1f * v.z;
    v.w = (v.w >= 0.f) ? v.w : 0.1f * v.w;
    out[i] = v;
}

extern "C" void kernel_launch(void* const* d_in, const int* in_sizes, int n_in,
                              void* d_out, int out_size, void* d_ws, size_t ws_size,
                              hipStream_t stream) {
    const float* q_points = (const float*)d_in[0];
    const float* s_points = (const float*)d_in[1];
    const float* feat     = (const float*)d_in[2];
    const float* conv_w   = (const float*)d_in[3];
    const float* gamma    = (const float*)d_in[4];
    const float* beta     = (const float*)d_in[5];
    const int*   inds     = (const int*)d_in[6];

    float* ws   = (float*)d_ws;
    float* sb   = ws;                              // 128
    float* par  = ws + 128;                        // GRIDM*128
    float* ftab = par + GRIDM * 128;               // 1,600,032 floats (bf16 table)
    float* sp4f = ftab + 1600032;                  // (NS+1)*4 = 200,004 floats
    float* qp4f = sp4f + 200004;                   // NQ*4 = 200,000 floats
    float* zmn  = qp4f + 200000;                   // NQ*CO floats (optional)

    const size_t need_tab = (size_t)(128 + GRIDM * 128 + 1600032 + 200004 + 200000) * 4;
    const size_t need_min = need_tab + (size_t)NQ * CO * 4;
    const bool has_tab = ws_size >= need_tab;
    const bool has_min = ws_size >= need_min;

    float* zmax = (float*)d_out;
    bf16x8* fbf = (bf16x8*)ftab;
    float4* sp4 = (float4*)sp4f;
    float4* qp4 = (float4*)qp4f;

    if (has_tab) {
        gc_tobf16<<<((NS + 1) * CF / 8 + 255) / 256, 256, 0, stream>>>(feat, fbf);
        gc_packpts<<<(NS + 1 + 255) / 256, 256, 0, stream>>>(s_points, q_points, sp4, qp4);
        if (has_min) {
            gc_mfma<true, true><<<GRIDM, 256, 0, stream>>>(
                q_points, s_points, feat, fbf, sp4, qp4, conv_w, inds, zmax, zmn, par);
        } else {
            gc_mfma<true, false><<<GRIDM, 256, 0, stream>>>(
                q_points, s_points, feat, fbf, sp4, qp4, conv_w, inds, zmax, nullptr, par);
        }
    } else {
        gc_mfma<false, false><<<GRIDM, 256, 0, stream>>>(
            q_points, s_points, feat, nullptr, nullptr, nullptr, conv_w, inds, zmax, nullptr, par);
    }
    gc_finalize<<<64, 256, 0, stream>>>(par, gamma, beta, sb);
    gc_bnact<<<(NQ * CO / 4 + 255) / 256, 256, 0, stream>>>(
        (float4*)d_out, (const float4*)zmn, sb, has_min && has_tab ? 1 : 0);
}

// Round 15
// 66.384 us; speedup vs baseline: 1.0819x; 1.0819x over previous
//
#include <hip/hip_runtime.h>
#include <hip/hip_bf16.h>
#include <math.h>

#define NQ 50000
#define NS 50000
#define KK 32
#define CF 64      // feat channels
#define CW 67      // conv input channels (3 + 64)
#define CO 64      // output channels
#define WAVES 4
#define GRIDG 2048            // gather kernel: 8 blocks/CU at <=64 VGPR
#define GRIDFB 1024           // fallback grid
#define GSFB (GRIDFB * WAVES)
#define PTILES ((NS + 1 + KK - 1) / KK)   // 1563 support tiles (incl. pad row)

typedef __attribute__((ext_vector_type(8))) short bf16x8;
typedef __attribute__((ext_vector_type(16))) float f32x16;

__device__ inline short f2b(float x) {
    union { __hip_bfloat16 b; short s; } u;
    u.b = __float2bfloat16(x);   // RNE
    return u.s;
}

__device__ inline bf16x8 pack2(const float4 a, const float4 b) {
    bf16x8 r;
    r[0] = f2b(a.x); r[1] = f2b(a.y); r[2] = f2b(a.z); r[3] = f2b(a.w);
    r[4] = f2b(b.x); r[5] = f2b(b.y); r[6] = f2b(b.z); r[7] = f2b(b.w);
    return r;
}

__device__ inline bf16x8 zero8() {
    bf16x8 r;
#pragma unroll
    for (int j = 0; j < 8; ++j) r[j] = 0;
    return r;
}

// B fragments: cols = output channels, k0..63 = Wf (w[o][3..66]), k64..66 = Wc.
__device__ inline void build_bfrag(const float* __restrict__ w, int col, int half,
                                   bf16x8 bfrag[5][2]) {
#pragma unroll
    for (int c = 0; c < 5; ++c) {
#pragma unroll
        for (int t = 0; t < 2; ++t) {
            const int o = t * 32 + col;
            bf16x8 r;
#pragma unroll
            for (int j = 0; j < 8; ++j) {
                const int k = c * 16 + half * 8 + j;
                float v = 0.f;
                if (k < 64)      v = w[o * CW + 3 + k];
                else if (k < 67) v = w[o * CW + (k - 64)];
                r[j] = f2b(v);
            }
            bfrag[c][t] = r;
        }
    }
}

// Prep: H[r][o] = feat[r]·Wf[o] + sp[r]·Wc[o] for r in [0,NS]; row NS = zeros.
// Dense MFMA GEMM over contiguous support tiles of 32 rows. Output bf16.
__global__ __launch_bounds__(256, 3) void gc_prep(
    const float* __restrict__ sp,
    const float* __restrict__ feat,
    const float* __restrict__ w,
    unsigned short* __restrict__ Hb)   // [NS+1][64]
{
    const int tid  = threadIdx.x;
    const int lane = tid & 63;
    const int wv   = tid >> 6;
    const int col  = lane & 31;
    const int half = lane >> 5;

    const int tile = blockIdx.x * WAVES + wv;
    if (tile >= PTILES) return;
    const int base = tile * 32;
    const int r    = base + col;          // support row this lane supplies (A row = lane&31)

    bf16x8 bfrag[5][2];
    build_bfrag(w, col, half, bfrag);

    bf16x8 A0, A1, A2, A3, a4;
    if (r < NS) {
        const float4* fp = (const float4*)(feat + (size_t)r * CF);
        A0 = pack2(fp[half * 2],      fp[half * 2 + 1]);
        A1 = pack2(fp[4 + half * 2],  fp[4 + half * 2 + 1]);
        A2 = pack2(fp[8 + half * 2],  fp[8 + half * 2 + 1]);
        A3 = pack2(fp[12 + half * 2], fp[12 + half * 2 + 1]);
        a4 = zero8();
        if (half == 0) {
            a4[0] = f2b(sp[r * 3 + 0]);
            a4[1] = f2b(sp[r * 3 + 1]);
            a4[2] = f2b(sp[r * 3 + 2]);
        }
    } else {
        A0 = zero8(); A1 = zero8(); A2 = zero8(); A3 = zero8(); a4 = zero8();
    }

    f32x16 acc0, acc1;
#pragma unroll
    for (int g = 0; g < 16; ++g) { acc0[g] = 0.f; acc1[g] = 0.f; }
    acc0 = __builtin_amdgcn_mfma_f32_32x32x16_bf16(A0, bfrag[0][0], acc0, 0, 0, 0);
    acc1 = __builtin_amdgcn_mfma_f32_32x32x16_bf16(A0, bfrag[0][1], acc1, 0, 0, 0);
    acc0 = __builtin_amdgcn_mfma_f32_32x32x16_bf16(A1, bfrag[1][0], acc0, 0, 0, 0);
    acc1 = __builtin_amdgcn_mfma_f32_32x32x16_bf16(A1, bfrag[1][1], acc1, 0, 0, 0);
    acc0 = __builtin_amdgcn_mfma_f32_32x32x16_bf16(A2, bfrag[2][0], acc0, 0, 0, 0);
    acc1 = __builtin_amdgcn_mfma_f32_32x32x16_bf16(A2, bfrag[2][1], acc1, 0, 0, 0);
    acc0 = __builtin_amdgcn_mfma_f32_32x32x16_bf16(A3, bfrag[3][0], acc0, 0, 0, 0);
    acc1 = __builtin_amdgcn_mfma_f32_32x32x16_bf16(A3, bfrag[3][1], acc1, 0, 0, 0);
    acc0 = __builtin_amdgcn_mfma_f32_32x32x16_bf16(a4, bfrag[4][0], acc0, 0, 0, 0);
    acc1 = __builtin_amdgcn_mfma_f32_32x32x16_bf16(a4, bfrag[4][1], acc1, 0, 0, 0);

    // C layout (verified m74/m101): col = lane&31, row = (g&3)+8*(g>>2)+4*(lane>>5)
#pragma unroll
    for (int g = 0; g < 16; ++g) {
        const int row = (g & 3) + 8 * (g >> 2) + 4 * half;
        const int rr  = base + row;
        if (rr <= NS) {
            Hb[(size_t)rr * CO + col]      = (unsigned short)f2b(acc0[g]);
            Hb[(size_t)rr * CO + 32 + col] = (unsigned short)f2b(acc1[g]);
        }
    }
}

// Main gather: lane = channel. Per query: 32 independent wave-wide row reads of
// H (1 line each, SGPR base via readlane), z = H - q·Wc (wave-uniform masked),
// per-lane max/sum/sumsq. No MFMA, no LDS in the loop, no cross-lane reduce.
template <bool MIN>
__global__ __launch_bounds__(256, 3) void gc_gather(
    const float* __restrict__ qp,
    const unsigned short* __restrict__ Hb,   // [NS+1][64] bf16 bits
    const float* __restrict__ w,
    const int*   __restrict__ inds,
    float* __restrict__ zmax,                // d_out [NQ][64]
    float* __restrict__ zmin,                // ws (optional)
    float* __restrict__ partials)            // [GRIDG][128]
{
    __shared__ float red[WAVES][128];

    const int tid  = threadIdx.x;
    const int lane = tid & 63;
    const int wv   = tid >> 6;

    // per-lane (channel) coordinate weights, register-resident
    const float Wc0 = w[lane * CW + 0];
    const float Wc1 = w[lane * CW + 1];
    const float Wc2 = w[lane * CW + 2];

    float csum = 0.f, csq = 0.f;

    for (int q = blockIdx.x * WAVES + wv; q < NQ; q += GRIDG * WAVES) {
        // lane n holds neighbor index n (lanes 32-63 duplicate)
        const int vii = inds[q * KK + (lane & 31)];
        const float qx = qp[q * 3 + 0];
        const float qy = qp[q * 3 + 1];
        const float qz = qp[q * 3 + 2];
        const float qwc = qx * Wc0 + qy * Wc1 + qz * Wc2;

        // issue all 32 row reads (independent; SGPR base per neighbor)
        unsigned int hr[KK];
        int iis[KK];
#pragma unroll
        for (int n = 0; n < KK; ++n) {
            const int iin = __builtin_amdgcn_readlane(vii, n);
            iis[n] = iin;
            hr[n] = Hb[(size_t)iin * CO + lane];   // global_load_ushort (zext)
        }

        float maxv = -1e38f, minv = 1e38f;
#pragma unroll
        for (int n = 0; n < KK; ++n) {
            union { unsigned int u; float f; } cv;
            cv.u = hr[n] << 16;                    // bf16 -> f32
            const float sub = (iis[n] < NS) ? qwc : 0.f;   // pad: H=0 and sub=0 -> z=0
            const float z = cv.f - sub;
            maxv = fmaxf(maxv, z);
            if (MIN) minv = fminf(minv, z);
            csum += z;
            csq = fmaf(z, z, csq);
        }
        zmax[q * CO + lane] = maxv;
        if (MIN) zmin[q * CO + lane] = minv;
    }

    red[wv][lane]      = csum;
    red[wv][64 + lane] = csq;
    __syncthreads();
    if (tid < 128) {
        partials[blockIdx.x * 128 + tid] =
            red[0][tid] + red[1][tid] + red[2][tid] + red[3][tid];
    }
}

// Fallback (ws too small for H table — not expected in practice): R4-style
// direct-f32 gather + MFMA, no tables. Correctness-only.
__global__ __launch_bounds__(256, 3) void gc_fb(
    const float* __restrict__ qp,
    const float* __restrict__ sp,
    const float* __restrict__ feat,
    const float* __restrict__ w,
    const int*   __restrict__ inds,
    float* __restrict__ zmax,
    float* __restrict__ partials)   // [GRIDFB][128]
{
    __shared__ float red[WAVES][128];
    const int tid  = threadIdx.x;
    const int lane = tid & 63;
    const int wv   = tid >> 6;
    const int col  = lane & 31;
    const int half = lane >> 5;

    bf16x8 bfrag[5][2];
    build_bfrag(w, col, half, bfrag);

    float csum0 = 0.f, csum1 = 0.f, csq0 = 0.f, csq1 = 0.f;

    for (int qb = blockIdx.x * WAVES; qb < NQ; qb += GSFB) {
        const int q = qb + wv;
        const int ii = inds[q * KK + col];
        const bool val = (ii < NS);
        bf16x8 A0, A1, A2, A3, a4;
        if (val) {
            const float4* fp = (const float4*)(feat + (size_t)ii * CF);
            A0 = pack2(fp[half * 2],      fp[half * 2 + 1]);
            A1 = pack2(fp[4 + half * 2],  fp[4 + half * 2 + 1]);
            A2 = pack2(fp[8 + half * 2],  fp[8 + half * 2 + 1]);
            A3 = pack2(fp[12 + half * 2], fp[12 + half * 2 + 1]);
            a4 = zero8();
            if (half == 0) {
                a4[0] = f2b(sp[ii * 3 + 0] - qp[q * 3 + 0]);
                a4[1] = f2b(sp[ii * 3 + 1] - qp[q * 3 + 1]);
                a4[2] = f2b(sp[ii * 3 + 2] - qp[q * 3 + 2]);
            }
        } else {
            A0 = zero8(); A1 = zero8(); A2 = zero8(); A3 = zero8(); a4 = zero8();
        }

        f32x16 acc0, acc1;
#pragma unroll
        for (int g = 0; g < 16; ++g) { acc0[g] = 0.f; acc1[g] = 0.f; }
        acc0 = __builtin_amdgcn_mfma_f32_32x32x16_bf16(A0, bfrag[0][0], acc0, 0, 0, 0);
        acc1 = __builtin_amdgcn_mfma_f32_32x32x16_bf16(A0, bfrag[0][1], acc1, 0, 0, 0);
        acc0 = __builtin_amdgcn_mfma_f32_32x32x16_bf16(A1, bfrag[1][0], acc0, 0, 0, 0);
        acc1 = __builtin_amdgcn_mfma_f32_32x32x16_bf16(A1, bfrag[1][1], acc1, 0, 0, 0);
        acc0 = __builtin_amdgcn_mfma_f32_32x32x16_bf16(A2, bfrag[2][0], acc0, 0, 0, 0);
        acc1 = __builtin_amdgcn_mfma_f32_32x32x16_bf16(A2, bfrag[2][1], acc1, 0, 0, 0);
        acc0 = __builtin_amdgcn_mfma_f32_32x32x16_bf16(A3, bfrag[3][0], acc0, 0, 0, 0);
        acc1 = __builtin_amdgcn_mfma_f32_32x32x16_bf16(A3, bfrag[3][1], acc1, 0, 0, 0);
        acc0 = __builtin_amdgcn_mfma_f32_32x32x16_bf16(a4, bfrag[4][0], acc0, 0, 0, 0);
        acc1 = __builtin_amdgcn_mfma_f32_32x32x16_bf16(a4, bfrag[4][1], acc1, 0, 0, 0);

        float m0 = acc0[0], m1 = acc1[0];
        float s0 = 0.f, s1 = 0.f, q0 = 0.f, q1 = 0.f;
#pragma unroll
        for (int g = 0; g < 16; ++g) {
            m0 = fmaxf(m0, acc0[g]); m1 = fmaxf(m1, acc1[g]);
            s0 += acc0[g]; s1 += acc1[g];
            q0 = fmaf(acc0[g], acc0[g], q0); q1 = fmaf(acc1[g], acc1[g], q1);
        }
        csum0 += s0; csum1 += s1; csq0 += q0; csq1 += q1;
        m0 = fmaxf(m0, __shfl_xor(m0, 32));
        m1 = fmaxf(m1, __shfl_xor(m1, 32));
        zmax[q * CO + half * 32 + col] = half ? m1 : m0;
    }

    csum0 += __shfl_xor(csum0, 32);
    csum1 += __shfl_xor(csum1, 32);
    csq0  += __shfl_xor(csq0, 32);
    csq1  += __shfl_xor(csq1, 32);
    if (lane < 32) {
        red[wv][col]      = csum0;
        red[wv][32 + col] = csum1;
        red[wv][64 + col] = csq0;
        red[wv][96 + col] = csq1;
    }
    __syncthreads();
    if (tid < 128) {
        partials[blockIdx.x * 128 + tid] =
            red[0][tid] + red[1][tid] + red[2][tid] + red[3][tid];
    }
}

// One block per channel: deterministic tree reduction over nblk partials.
__global__ void gc_finalize(const float* __restrict__ partials, int nblk,
                            const float* __restrict__ gamma,
                            const float* __restrict__ beta,
                            float* __restrict__ sb)
{
    __shared__ double rs[256], rq[256];
    const int o = blockIdx.x;
    const int t = threadIdx.x;
    double s = 0.0, qq = 0.0;
    for (int b = t; b < nblk; b += 256) {
        s  += (double)partials[b * 128 + o];
        qq += (double)partials[b * 128 + 64 + o];
    }
    rs[t] = s; rq[t] = qq;
    __syncthreads();
    for (int w2 = 128; w2 > 0; w2 >>= 1) {
        if (t < w2) { rs[t] += rs[t + w2]; rq[t] += rq[t + w2]; }
        __syncthreads();
    }
    if (t == 0) {
        const double n = (double)NQ * (double)KK;
        const double mean = rs[0] / n;
        const double var  = rq[0] / n - mean * mean;
        const float sc = gamma[o] * (float)(1.0 / sqrt(var + 1e-5));
        const float bi = beta[o] - (float)mean * sc;
        sb[o]      = sc;
        sb[64 + o] = bi;
    }
}

// out = leaky(scale * z + bias), in place on d_out (float4-wide).
__global__ void gc_bnact(float4* __restrict__ out,
                         const float4* __restrict__ zmin,
                         const float* __restrict__ sb,
                         int has_min)
{
    const int i  = blockIdx.x * 256 + threadIdx.x;   // < NQ*CO/4
    const int ob = (i & 15) * 4;
    const float4 s4 = *(const float4*)(sb + ob);
    const float4 b4 = *(const float4*)(sb + 64 + ob);
    float4 z4 = out[i];
    if (has_min && (s4.x < 0.f || s4.y < 0.f || s4.z < 0.f || s4.w < 0.f)) {
        const float4 n4 = zmin[i];
        if (s4.x < 0.f) z4.x = n4.x;
        if (s4.y < 0.f) z4.y = n4.y;
        if (s4.z < 0.f) z4.z = n4.z;
        if (s4.w < 0.f) z4.w = n4.w;
    }
    float4 v;
    v.x = s4.x * z4.x + b4.x;
    v.y = s4.y * z4.y + b4.y;
    v.z = s4.z * z4.z + b4.z;
    v.w = s4.w * z4.w + b4.w;
    v.x = (v.x >= 0.f) ? v.x : 0.1f * v.x;
    v.y = (v.y >= 0.f) ? v.y : 0.1f * v.y;
    v.z = (v.z >= 0.f) ? v.z : 0.1f * v.z;
    v.w = (v.w >= 0.f) ? v.w : 0.1f * v.w;
    out[i] = v;
}

extern "C" void kernel_launch(void* const* d_in, const int* in_sizes, int n_in,
                              void* d_out, int out_size, void* d_ws, size_t ws_size,
                              hipStream_t stream) {
    const float* q_points = (const float*)d_in[0];
    const float* s_points = (const float*)d_in[1];
    const float* feat     = (const float*)d_in[2];
    const float* conv_w   = (const float*)d_in[3];
    const float* gamma    = (const float*)d_in[4];
    const float* beta     = (const float*)d_in[5];
    const int*   inds     = (const int*)d_in[6];

    float* ws  = (float*)d_ws;
    float* sb  = ws;                               // 128 floats
    float* par = ws + 128;                         // GRIDG*128 floats
    float* Hf  = par + GRIDG * 128;                // (NS+1)*64 ushort = 1,600,032 floats
    float* zmn = Hf + 1600032;                     // NQ*CO floats (optional)

    const size_t need_tab = (size_t)(128 + GRIDG * 128 + 1600032) * 4;   // ~7.45 MB
    const size_t need_min = need_tab + (size_t)NQ * CO * 4;              // ~20.2 MB
    const bool has_tab = ws_size >= need_tab;
    const bool has_min = ws_size >= need_min;

    float* zmax = (float*)d_out;
    unsigned short* Hb = (unsigned short*)Hf;

    if (has_tab) {
        gc_prep<<<(PTILES + WAVES - 1) / WAVES, 256, 0, stream>>>(
            s_points, feat, conv_w, Hb);
        if (has_min) {
            gc_gather<true><<<GRIDG, 256, 0, stream>>>(
                q_points, Hb, conv_w, inds, zmax, zmn, par);
        } else {
            gc_gather<false><<<GRIDG, 256, 0, stream>>>(
                q_points, Hb, conv_w, inds, zmax, nullptr, par);
        }
        gc_finalize<<<64, 256, 0, stream>>>(par, GRIDG, gamma, beta, sb);
    } else {
        gc_fb<<<GRIDFB, 256, 0, stream>>>(
            q_points, s_points, feat, conv_w, inds, zmax, par);
        gc_finalize<<<64, 256, 0, stream>>>(par, GRIDFB, gamma, beta, sb);
    }
    gc_bnact<<<(NQ * CO / 4 + 255) / 256, 256, 0, stream>>>(
        (float4*)d_out, (const float4*)zmn, sb, (has_min && has_tab) ? 1 : 0);
}